// Round 5
// baseline (969.367 us; speedup 1.0000x reference)
//
#include <hip/hip_runtime.h>
#include <stdint.h>

#define D 64
constexpr float NEG_SLOPE = 0.2f;
#define BKT_SHIFT 7
#define BKT_NODES 128   // nodes per bucket

// ce[l] = sum_d We_l[d] * ae_l[d]
__global__ void k_ce(const float* __restrict__ We1, const float* __restrict__ ae1,
                     const float* __restrict__ We2, const float* __restrict__ ae2,
                     float* __restrict__ ce){
  int lane = threadIdx.x;
  float p1 = We1[lane] * ae1[lane];
  float p2 = We2[lane] * ae2[lane];
  #pragma unroll
  for (int off = 32; off; off >>= 1){ p1 += __shfl_xor(p1, off); p2 += __shfl_xor(p2, off); }
  if (lane == 0){ ce[0] = p1; ce[1] = p2; }
}

// h = X @ W — persistent blocks: stage W once, grid-stride rows.
// fused asrc[r]=h.as, adst[r]=h.ad
__global__ __launch_bounds__(256) void k_gemm_dots(
    const float* __restrict__ X, const float* __restrict__ W,
    const float* __restrict__ a_s, const float* __restrict__ a_d,
    float* __restrict__ H, float* __restrict__ asrc, float* __restrict__ adst, int n)
{
  __shared__ float sW[D * D];
  {
    const float4* Wv = (const float4*)W;
    float4* sWv = (float4*)sW;
    #pragma unroll
    for (int t = threadIdx.x; t < D * D / 4; t += 256) sWv[t] = Wv[t];
  }
  int lane = threadIdx.x & 63;
  int wid  = threadIdx.x >> 6;
  float asv = a_s[lane], adv = a_d[lane];
  __syncthreads();
  int stride = gridDim.x * 4;
  for (int r = blockIdx.x * 4 + wid; r < n; r += stride){
    float xv = X[(size_t)r * D + lane];
    float acc = 0.f;
    #pragma unroll
    for (int k = 0; k < D; ++k){
      float xk = __shfl(xv, k);
      acc = fmaf(xk, sW[k * D + lane], acc);
    }
    H[(size_t)r * D + lane] = acc;
    float ps = acc * asv, pd = acc * adv;
    #pragma unroll
    for (int off = 32; off; off >>= 1){ ps += __shfl_xor(ps, off); pd += __shfl_xor(pd, off); }
    if (lane == 0){ asrc[r] = ps; adst[r] = pd; }
  }
}

// ---------------- CSR build (once per call) ----------------

__global__ void k_zero(int* __restrict__ deg, int n){
  int i = blockIdx.x * blockDim.x + threadIdx.x;
  if (i < n) deg[i] = 0;
}

__global__ void k_hist(const int* __restrict__ dst, int* __restrict__ deg, int e){
  int i = blockIdx.x * blockDim.x + threadIdx.x;
  if (i < e) atomicAdd(&deg[dst[i]], 1);
}

// block-level inclusive scan (256/block) + block sums
__global__ __launch_bounds__(256) void k_scan1(const int* __restrict__ deg,
    int* __restrict__ incl, int* __restrict__ bsum, int n){
  __shared__ int s[256];
  int tid = threadIdx.x;
  int idx = blockIdx.x * 256 + tid;
  int v = (idx < n) ? deg[idx] : 0;
  s[tid] = v; __syncthreads();
  #pragma unroll
  for (int off = 1; off < 256; off <<= 1){
    int t = (tid >= off) ? s[tid - off] : 0;
    __syncthreads();
    s[tid] += t;
    __syncthreads();
  }
  if (idx < n) incl[idx] = s[tid];
  if (tid == 255) bsum[blockIdx.x] = s[255];
}

// single-wave exclusive scan of block sums (nb <= 512)
__global__ void k_scan2(int* __restrict__ bsum, int nb){
  int lane = threadIdx.x;                // 64 threads
  int per = (nb + 63) / 64;              // <= 8
  int base = lane * per;
  int local[8];
  int s = 0;
  #pragma unroll
  for (int k = 0; k < 8; ++k){
    int idx = base + k;
    int v = (k < per && idx < nb) ? bsum[idx] : 0;
    local[k] = v; s += v;
  }
  int inc = s;
  #pragma unroll
  for (int off = 1; off < 64; off <<= 1){
    int t = __shfl_up(inc, off);
    if (lane >= off) inc += t;
  }
  int run = inc - s;                     // exclusive prefix for this lane
  #pragma unroll
  for (int k = 0; k < 8; ++k){
    int idx = base + k;
    if (k < per && idx < nb){ int v = local[k]; bsum[idx] = run; run += v; }
  }
}

// rowptr[i+1] = incl[i]+bsum_excl[blk]; rowptr[0]=0
__global__ void k_scan3(const int* __restrict__ incl, const int* __restrict__ bsum,
    int* __restrict__ rowptr, int n){
  int idx = blockIdx.x * 256 + threadIdx.x;
  if (idx >= n) return;
  rowptr[idx + 1] = incl[idx] + bsum[blockIdx.x];
  if (idx == 0) rowptr[0] = 0;
}

// bucket cursor init: bcur[b] = rowptr[b*128]
__global__ void k_bcur(const int* __restrict__ rowptr, int* __restrict__ bcur, int nbkt){
  int b = blockIdx.x * blockDim.x + threadIdx.x;
  if (b < nbkt) bcur[b] = rowptr[b << BKT_SHIFT];
}

// pass 1: scatter edges into dst-bucket regions (dense per bucket -> good
// line coverage). Pack src (17b) | dstLocal (7b) << 17, ea bits.
__global__ void k_scatter1(const int* __restrict__ src, const int* __restrict__ dst,
    const float* __restrict__ ea, int* __restrict__ bcur,
    int2* __restrict__ staging, int e){
  int i = blockIdx.x * blockDim.x + threadIdx.x;
  if (i >= e) return;
  int d = dst[i];
  int b = d >> BKT_SHIFT;
  int pos = atomicAdd(&bcur[b], 1);
  staging[pos] = make_int2(src[i] | ((d & (BKT_NODES - 1)) << 17), __float_as_int(ea[i]));
}

// pass 2: one block per bucket; finalize within-bucket CSR positions using
// LDS per-node cursors. Reads/writes confined to the bucket's ~16KB window.
__global__ __launch_bounds__(256) void k_scatter2(const int* __restrict__ rowptr,
    const int2* __restrict__ staging, int2* __restrict__ edges, int n){
  __shared__ int lrp[BKT_NODES + 1];
  __shared__ int cnt[BKT_NODES];
  int b = blockIdx.x;
  int node0 = b << BKT_SHIFT;
  int nn = min(BKT_NODES, n - node0);
  int tid = threadIdx.x;
  if (tid <= nn) lrp[tid] = rowptr[node0 + tid];
  if (tid < BKT_NODES) cnt[tid] = 0;
  __syncthreads();
  int jstart = lrp[0], jend = lrp[nn];
  for (int j = jstart + tid; j < jend; j += 256){
    int2 w = staging[j];
    int dl = w.x >> 17;
    int pos = lrp[dl] + atomicAdd(&cnt[dl], 1);
    edges[pos] = make_int2(w.x & 0x1FFFF, w.y);
  }
}

// ---------------- fused per-node softmax + aggregation ----------------
__global__ __launch_bounds__(256) void k_node_fused(
    const int* __restrict__ rowptr, const int2* __restrict__ edges,
    const float* __restrict__ asrc, const float* __restrict__ adst,
    const float* __restrict__ ce, int ce_idx,
    const float* __restrict__ H, const float* __restrict__ bias,
    float* __restrict__ out, int n, int relu)
{
  int v = blockIdx.x * 4 + (threadIdx.x >> 6);
  int lane = threadIdx.x & 63;
  if (v >= n) return;
  int start = rowptr[v], end = rowptr[v + 1];
  int deg = end - start;
  float bv = bias[lane];
  if (deg == 0){
    float r = relu ? fmaxf(bv, 0.f) : bv;
    out[(size_t)v * D + lane] = r;
    return;
  }
  float adv = adst[v];
  float cev = ce[ce_idx];
  float acc = 0.f;
  float inv;
  if (deg <= 64){
    int my_s = 0; float my_a = -1e30f;
    if (lane < deg){
      int2 pr = edges[start + lane];
      my_s = pr.x;
      float a = asrc[pr.x] + adv + __int_as_float(pr.y) * cev;
      my_a = a > 0.f ? a : NEG_SLOPE * a;
    }
    float m = my_a;
    #pragma unroll
    for (int off = 32; off; off >>= 1) m = fmaxf(m, __shfl_xor(m, off));
    float my_e = (lane < deg) ? __expf(my_a - m) : 0.f;
    float ss = my_e;
    #pragma unroll
    for (int off = 32; off; off >>= 1) ss += __shfl_xor(ss, off);
    inv = 1.f / (ss + 1e-16f);
    for (int k = 0; k < deg; ++k){
      int s   = __shfl(my_s, k);
      float w = __shfl(my_e, k);
      acc = fmaf(H[(size_t)s * D + lane], w, acc);
    }
  } else {
    float m = -1e30f;
    for (int j = start + lane; j < end; j += 64){
      int2 pr = edges[j];
      float a = asrc[pr.x] + adv + __int_as_float(pr.y) * cev;
      a = a > 0.f ? a : NEG_SLOPE * a;
      m = fmaxf(m, a);
    }
    #pragma unroll
    for (int off = 32; off; off >>= 1) m = fmaxf(m, __shfl_xor(m, off));
    float ss = 0.f;
    for (int j0 = start; j0 < end; j0 += 64){
      int j = j0 + lane;
      int my_s = 0; float my_e = 0.f;
      if (j < end){
        int2 pr = edges[j];
        float a = asrc[pr.x] + adv + __int_as_float(pr.y) * cev;
        a = a > 0.f ? a : NEG_SLOPE * a;
        my_e = __expf(a - m);
        my_s = pr.x;
      }
      ss += my_e;
      int cnt = min(64, end - j0);
      for (int k = 0; k < cnt; ++k){
        int s   = __shfl(my_s, k);
        float w = __shfl(my_e, k);
        acc = fmaf(H[(size_t)s * D + lane], w, acc);
      }
    }
    #pragma unroll
    for (int off = 32; off; off >>= 1) ss += __shfl_xor(ss, off);
    inv = 1.f / (ss + 1e-16f);
  }
  float r = acc * inv + bv;
  if (relu) r = fmaxf(r, 0.f);
  out[(size_t)v * D + lane] = r;
}

extern "C" void kernel_launch(void* const* d_in, const int* in_sizes, int n_in,
                              void* d_out, int out_size, void* d_ws, size_t ws_size,
                              hipStream_t stream)
{
  const float* x    = (const float*)d_in[0];
  const int*   ei   = (const int*)d_in[1];    // integer inputs arrive as int32
  const float* ea   = (const float*)d_in[2];
  const float* W1   = (const float*)d_in[3];
  const float* We1  = (const float*)d_in[4];
  const float* as1  = (const float*)d_in[5];
  const float* ad1  = (const float*)d_in[6];
  const float* ae1  = (const float*)d_in[7];
  const float* b1   = (const float*)d_in[8];
  const float* W2   = (const float*)d_in[9];
  const float* We2  = (const float*)d_in[10];
  const float* as2  = (const float*)d_in[11];
  const float* ad2  = (const float*)d_in[12];
  const float* ae2  = (const float*)d_in[13];
  const float* b2   = (const float*)d_in[14];
  float* out = (float*)d_out;

  int n = in_sizes[0] / D;     // 100000
  int e = in_sizes[1] / 2;     // 1600000
  const int* srcp = ei;
  const int* dstp = ei + e;

  int nb   = (n + 255) / 256;            // scan blocks (391)
  int nbkt = (n + BKT_NODES - 1) / BKT_NODES;  // 782 buckets

  char* p = (char*)d_ws;
  float* buf_h   = (float*)p;  p += (size_t)n * D * 4;
  float* buf_x2  = (float*)p;  p += (size_t)n * D * 4;
  float* asrc    = (float*)p;  p += (size_t)n * 4;
  float* adst    = (float*)p;  p += (size_t)n * 4;
  int*   deg     = (int*)p;    p += (size_t)n * 4;
  int*   incl    = (int*)p;    p += (size_t)n * 4;
  int*   rowptr  = (int*)p;    p += (size_t)(n + 1) * 4;
  int*   bsum    = (int*)p;    p += (size_t)(nb + 1) * 4;
  int*   bcur    = (int*)p;    p += (size_t)(nbkt + 1) * 4;
  float* ce      = (float*)p;  p += 64;               // keep 8B alignment after
  int2*  edges   = (int2*)p;   p += (size_t)e * 8;
  // staging aliases buf_x2 (dead until layer-1 k_node_fused writes buf_x2):
  // n*D*4 = 25.6MB >= e*8 = 12.8MB ✓
  int2*  staging = (int2*)buf_x2;

  int gE  = (e + 255) / 256;
  int gR  = (n + 3) / 4;      // fused: wave per node, 4 per block

  // ---- CSR build ----
  k_ce<<<1, 64, 0, stream>>>(We1, ae1, We2, ae2, ce);
  k_zero<<<nb, 256, 0, stream>>>(deg, n);
  k_hist<<<gE, 256, 0, stream>>>(dstp, deg, e);
  k_scan1<<<nb, 256, 0, stream>>>(deg, incl, bsum, n);
  k_scan2<<<1, 64, 0, stream>>>(bsum, nb);
  k_scan3<<<nb, 256, 0, stream>>>(incl, bsum, rowptr, n);
  k_bcur<<<(nbkt + 255) / 256, 256, 0, stream>>>(rowptr, bcur, nbkt);
  k_scatter1<<<gE, 256, 0, stream>>>(srcp, dstp, ea, bcur, staging, e);
  k_scatter2<<<nbkt, 256, 0, stream>>>(rowptr, staging, edges, n);

  // ---- layer 1 ----
  k_gemm_dots<<<1024, 256, 0, stream>>>(x, W1, as1, ad1, buf_h, asrc, adst, n);
  k_node_fused<<<gR, 256, 0, stream>>>(rowptr, edges, asrc, adst, ce, 0, buf_h, b1, buf_x2, n, 1);

  // ---- layer 2 ----
  k_gemm_dots<<<1024, 256, 0, stream>>>(buf_x2, W2, as2, ad2, buf_h, asrc, adst, n);
  k_node_fused<<<gR, 256, 0, stream>>>(rowptr, edges, asrc, adst, ce, 1, buf_h, b2, out, n, 0);
}

// Round 6
// 685.159 us; speedup vs baseline: 1.4148x; 1.4148x over previous
//
#include <hip/hip_runtime.h>
#include <stdint.h>

#define D 64
constexpr float NEG_SLOPE = 0.2f;

// ce[l] = sum_d We_l[d] * ae_l[d]
__global__ void k_ce(const float* __restrict__ We1, const float* __restrict__ ae1,
                     const float* __restrict__ We2, const float* __restrict__ ae2,
                     float* __restrict__ ce){
  int lane = threadIdx.x;
  float p1 = We1[lane] * ae1[lane];
  float p2 = We2[lane] * ae2[lane];
  #pragma unroll
  for (int off = 32; off; off >>= 1){ p1 += __shfl_xor(p1, off); p2 += __shfl_xor(p2, off); }
  if (lane == 0){ ce[0] = p1; ce[1] = p2; }
}

// h = X @ W — persistent blocks: stage W once, grid-stride rows.
// fused asrc[r]=h.as, adst[r]=h.ad
__global__ __launch_bounds__(256) void k_gemm_dots(
    const float* __restrict__ X, const float* __restrict__ W,
    const float* __restrict__ a_s, const float* __restrict__ a_d,
    float* __restrict__ H, float* __restrict__ asrc, float* __restrict__ adst, int n)
{
  __shared__ float sW[D * D];
  {
    const float4* Wv = (const float4*)W;
    float4* sWv = (float4*)sW;
    #pragma unroll
    for (int t = threadIdx.x; t < D * D / 4; t += 256) sWv[t] = Wv[t];
  }
  int lane = threadIdx.x & 63;
  int wid  = threadIdx.x >> 6;
  float asv = a_s[lane], adv = a_d[lane];
  __syncthreads();
  int stride = gridDim.x * 4;
  for (int r = blockIdx.x * 4 + wid; r < n; r += stride){
    float xv = X[(size_t)r * D + lane];
    float acc = 0.f;
    #pragma unroll
    for (int k = 0; k < D; ++k){
      float xk = __shfl(xv, k);
      acc = fmaf(xk, sW[k * D + lane], acc);
    }
    H[(size_t)r * D + lane] = acc;
    float ps = acc * asv, pd = acc * adv;
    #pragma unroll
    for (int off = 32; off; off >>= 1){ ps += __shfl_xor(ps, off); pd += __shfl_xor(pd, off); }
    if (lane == 0){ asrc[r] = ps; adst[r] = pd; }
  }
}

// ---------------- CSR build (once per call) ----------------

__global__ void k_hist(const int* __restrict__ dst, int* __restrict__ deg, int e){
  int i = blockIdx.x * blockDim.x + threadIdx.x;
  if (i < e) atomicAdd(&deg[dst[i]], 1);
}

// block-level inclusive scan (256/block) + block sums
__global__ __launch_bounds__(256) void k_scan1(const int* __restrict__ deg,
    int* __restrict__ incl, int* __restrict__ bsum, int n){
  __shared__ int s[256];
  int tid = threadIdx.x;
  int idx = blockIdx.x * 256 + tid;
  int v = (idx < n) ? deg[idx] : 0;
  s[tid] = v; __syncthreads();
  #pragma unroll
  for (int off = 1; off < 256; off <<= 1){
    int t = (tid >= off) ? s[tid - off] : 0;
    __syncthreads();
    s[tid] += t;
    __syncthreads();
  }
  if (idx < n) incl[idx] = s[tid];
  if (tid == 255) bsum[blockIdx.x] = s[255];
}

// single-wave exclusive scan of block sums (nb <= 512)
__global__ void k_scan2(int* __restrict__ bsum, int nb){
  int lane = threadIdx.x;                // 64 threads
  int per = (nb + 63) / 64;              // <= 8
  int base = lane * per;
  int local[8];
  int s = 0;
  #pragma unroll
  for (int k = 0; k < 8; ++k){
    int idx = base + k;
    int v = (k < per && idx < nb) ? bsum[idx] : 0;
    local[k] = v; s += v;
  }
  int inc = s;
  #pragma unroll
  for (int off = 1; off < 64; off <<= 1){
    int t = __shfl_up(inc, off);
    if (lane >= off) inc += t;
  }
  int run = inc - s;                     // exclusive prefix for this lane
  #pragma unroll
  for (int k = 0; k < 8; ++k){
    int idx = base + k;
    if (k < per && idx < nb){ int v = local[k]; bsum[idx] = run; run += v; }
  }
}

// rowptr[i+1] = incl[i]+bsum_excl[blk]; cursor[i] = row start; rowptr[0]=0
__global__ void k_scan3(const int* __restrict__ deg, const int* __restrict__ incl,
    const int* __restrict__ bsum, int* __restrict__ rowptr, int* __restrict__ cursor, int n){
  int idx = blockIdx.x * 256 + threadIdx.x;
  if (idx >= n) return;
  int inc = incl[idx] + bsum[blockIdx.x];
  rowptr[idx + 1] = inc;
  cursor[idx] = inc - deg[idx];
  if (idx == 0) rowptr[0] = 0;
}

// one 8B random store per edge (src, ea-bits packed); per-node cursors
// (100k counters -> ~16 avg collisions; contention-light, line-traffic bound)
__global__ void k_scatter(const int* __restrict__ src, const int* __restrict__ dst,
    const float* __restrict__ ea, int* __restrict__ cursor,
    int2* __restrict__ edges, int e){
  int i = blockIdx.x * blockDim.x + threadIdx.x;
  if (i >= e) return;
  int d = dst[i];
  int pos = atomicAdd(&cursor[d], 1);
  edges[pos] = make_int2(src[i], __float_as_int(ea[i]));
}

// ---------------- fused per-node softmax + aggregation ----------------
// wave per node, lane=feature. Phase A: lane l holds edge l's (src, alpha) in
// registers (deg<=64 fast path); shfl-reduce max & denom. Phase B: broadcast
// (src_k, e_k) via shfl, accumulate coalesced H rows.
__global__ __launch_bounds__(256) void k_node_fused(
    const int* __restrict__ rowptr, const int2* __restrict__ edges,
    const float* __restrict__ asrc, const float* __restrict__ adst,
    const float* __restrict__ ce, int ce_idx,
    const float* __restrict__ H, const float* __restrict__ bias,
    float* __restrict__ out, int n, int relu)
{
  int v = blockIdx.x * 4 + (threadIdx.x >> 6);
  int lane = threadIdx.x & 63;
  if (v >= n) return;
  int start = rowptr[v], end = rowptr[v + 1];
  int deg = end - start;
  float bv = bias[lane];
  if (deg == 0){
    float r = relu ? fmaxf(bv, 0.f) : bv;
    out[(size_t)v * D + lane] = r;
    return;
  }
  float adv = adst[v];
  float cev = ce[ce_idx];
  float acc = 0.f;
  float inv;
  if (deg <= 64){
    int my_s = 0; float my_a = -1e30f;
    if (lane < deg){
      int2 pr = edges[start + lane];
      my_s = pr.x;
      float a = asrc[pr.x] + adv + __int_as_float(pr.y) * cev;
      my_a = a > 0.f ? a : NEG_SLOPE * a;
    }
    float m = my_a;
    #pragma unroll
    for (int off = 32; off; off >>= 1) m = fmaxf(m, __shfl_xor(m, off));
    float my_e = (lane < deg) ? __expf(my_a - m) : 0.f;
    float ss = my_e;
    #pragma unroll
    for (int off = 32; off; off >>= 1) ss += __shfl_xor(ss, off);
    inv = 1.f / (ss + 1e-16f);
    for (int k = 0; k < deg; ++k){
      int s   = __shfl(my_s, k);
      float w = __shfl(my_e, k);
      acc = fmaf(H[(size_t)s * D + lane], w, acc);
    }
  } else {
    float m = -1e30f;
    for (int j = start + lane; j < end; j += 64){
      int2 pr = edges[j];
      float a = asrc[pr.x] + adv + __int_as_float(pr.y) * cev;
      a = a > 0.f ? a : NEG_SLOPE * a;
      m = fmaxf(m, a);
    }
    #pragma unroll
    for (int off = 32; off; off >>= 1) m = fmaxf(m, __shfl_xor(m, off));
    float ss = 0.f;
    for (int j0 = start; j0 < end; j0 += 64){
      int j = j0 + lane;
      int my_s = 0; float my_e = 0.f;
      if (j < end){
        int2 pr = edges[j];
        float a = asrc[pr.x] + adv + __int_as_float(pr.y) * cev;
        a = a > 0.f ? a : NEG_SLOPE * a;
        my_e = __expf(a - m);
        my_s = pr.x;
      }
      ss += my_e;
      int cnt = min(64, end - j0);
      for (int k = 0; k < cnt; ++k){
        int s   = __shfl(my_s, k);
        float w = __shfl(my_e, k);
        acc = fmaf(H[(size_t)s * D + lane], w, acc);
      }
    }
    #pragma unroll
    for (int off = 32; off; off >>= 1) ss += __shfl_xor(ss, off);
    inv = 1.f / (ss + 1e-16f);
  }
  float r = acc * inv + bv;
  if (relu) r = fmaxf(r, 0.f);
  out[(size_t)v * D + lane] = r;
}

extern "C" void kernel_launch(void* const* d_in, const int* in_sizes, int n_in,
                              void* d_out, int out_size, void* d_ws, size_t ws_size,
                              hipStream_t stream)
{
  const float* x    = (const float*)d_in[0];
  const int*   ei   = (const int*)d_in[1];    // integer inputs arrive as int32
  const float* ea   = (const float*)d_in[2];
  const float* W1   = (const float*)d_in[3];
  const float* We1  = (const float*)d_in[4];
  const float* as1  = (const float*)d_in[5];
  const float* ad1  = (const float*)d_in[6];
  const float* ae1  = (const float*)d_in[7];
  const float* b1   = (const float*)d_in[8];
  const float* W2   = (const float*)d_in[9];
  const float* We2  = (const float*)d_in[10];
  const float* as2  = (const float*)d_in[11];
  const float* ad2  = (const float*)d_in[12];
  const float* ae2  = (const float*)d_in[13];
  const float* b2   = (const float*)d_in[14];
  float* out = (float*)d_out;

  int n = in_sizes[0] / D;     // 100000
  int e = in_sizes[1] / 2;     // 1600000
  const int* srcp = ei;
  const int* dstp = ei + e;

  int nb = (n + 255) / 256;    // scan blocks (391)

  char* p = (char*)d_ws;
  float* buf_h   = (float*)p;  p += (size_t)n * D * 4;
  float* buf_x2  = (float*)p;  p += (size_t)n * D * 4;
  float* asrc    = (float*)p;  p += (size_t)n * 4;
  float* adst    = (float*)p;  p += (size_t)n * 4;
  int*   deg     = (int*)p;    p += (size_t)n * 4;
  int*   incl    = (int*)p;    p += (size_t)n * 4;
  int*   rowptr  = (int*)p;    p += (size_t)(n + 1) * 4;
  int*   cursor  = (int*)p;    p += (size_t)n * 4;
  int*   bsum    = (int*)p;    p += (size_t)(nb + 1) * 4;
  float* ce      = (float*)p;  p += 64;               // keep 8B alignment after
  int2*  edges   = (int2*)p;   p += (size_t)e * 8;

  int gE  = (e + 255) / 256;
  int gR  = (n + 3) / 4;      // wave per node, 4 per block

  // ---- CSR build ----
  hipMemsetAsync(deg, 0, (size_t)n * 4, stream);
  k_ce<<<1, 64, 0, stream>>>(We1, ae1, We2, ae2, ce);
  k_hist<<<gE, 256, 0, stream>>>(dstp, deg, e);
  k_scan1<<<nb, 256, 0, stream>>>(deg, incl, bsum, n);
  k_scan2<<<1, 64, 0, stream>>>(bsum, nb);
  k_scan3<<<nb, 256, 0, stream>>>(deg, incl, bsum, rowptr, cursor, n);
  k_scatter<<<gE, 256, 0, stream>>>(srcp, dstp, ea, cursor, edges, e);

  // ---- layer 1 ----
  k_gemm_dots<<<1024, 256, 0, stream>>>(x, W1, as1, ad1, buf_h, asrc, adst, n);
  k_node_fused<<<gR, 256, 0, stream>>>(rowptr, edges, asrc, adst, ce, 0, buf_h, b1, buf_x2, n, 1);

  // ---- layer 2 ----
  k_gemm_dots<<<1024, 256, 0, stream>>>(buf_x2, W2, as2, ad2, buf_h, asrc, adst, n);
  k_node_fused<<<gR, 256, 0, stream>>>(rowptr, edges, asrc, adst, ce, 1, buf_h, b2, out, n, 0);
}

// Round 7
// 546.694 us; speedup vs baseline: 1.7731x; 1.2533x over previous
//
#include <hip/hip_runtime.h>
#include <stdint.h>

#define D 64
constexpr float NEG_SLOPE = 0.2f;
#define NPB_SHIFT 9
#define NPB 512          // nodes per bucket
#define PCHUNK 4096      // edges per partition chunk

// ce[l] = sum_d We_l[d] * ae_l[d]
__global__ void k_ce(const float* __restrict__ We1, const float* __restrict__ ae1,
                     const float* __restrict__ We2, const float* __restrict__ ae2,
                     float* __restrict__ ce){
  int lane = threadIdx.x;
  float p1 = We1[lane] * ae1[lane];
  float p2 = We2[lane] * ae2[lane];
  #pragma unroll
  for (int off = 32; off; off >>= 1){ p1 += __shfl_xor(p1, off); p2 += __shfl_xor(p2, off); }
  if (lane == 0){ ce[0] = p1; ce[1] = p2; }
}

// h = X @ W — persistent blocks; fused asrc/adst dot products
__global__ __launch_bounds__(256) void k_gemm_dots(
    const float* __restrict__ X, const float* __restrict__ W,
    const float* __restrict__ a_s, const float* __restrict__ a_d,
    float* __restrict__ H, float* __restrict__ asrc, float* __restrict__ adst, int n)
{
  __shared__ float sW[D * D];
  {
    const float4* Wv = (const float4*)W;
    float4* sWv = (float4*)sW;
    #pragma unroll
    for (int t = threadIdx.x; t < D * D / 4; t += 256) sWv[t] = Wv[t];
  }
  int lane = threadIdx.x & 63;
  int wid  = threadIdx.x >> 6;
  float asv = a_s[lane], adv = a_d[lane];
  __syncthreads();
  int stride = gridDim.x * 4;
  for (int r = blockIdx.x * 4 + wid; r < n; r += stride){
    float xv = X[(size_t)r * D + lane];
    float acc = 0.f;
    #pragma unroll
    for (int k = 0; k < D; ++k){
      float xk = __shfl(xv, k);
      acc = fmaf(xk, sW[k * D + lane], acc);
    }
    H[(size_t)r * D + lane] = acc;
    float ps = acc * asv, pd = acc * adv;
    #pragma unroll
    for (int off = 32; off; off >>= 1){ ps += __shfl_xor(ps, off); pd += __shfl_xor(pd, off); }
    if (lane == 0){ asrc[r] = ps; adst[r] = pd; }
  }
}

// ---------------- contention-free CSR build ----------------

// per-chunk bucket histogram -> C[b*nchunk + c]  (no global atomics)
__global__ __launch_bounds__(256) void k_bhist(const int* __restrict__ dst,
    int* __restrict__ C, int nchunk, int e, int nbkt){
  __shared__ int hist[256];
  int tid = threadIdx.x, c = blockIdx.x;
  if (tid < nbkt) hist[tid] = 0;
  __syncthreads();
  int c0 = c * PCHUNK;
  #pragma unroll
  for (int k = 0; k < PCHUNK / 256; ++k){
    int i = c0 + tid + (k << 8);
    if (i < e) atomicAdd(&hist[dst[i] >> NPB_SHIFT], 1);
  }
  __syncthreads();
  if (tid < nbkt) C[tid * nchunk + c] = hist[tid];
}

// per-bucket exclusive scan of C over chunks; bucket totals (nchunk <= 512)
__global__ __launch_bounds__(512) void k_cscan(int* __restrict__ C,
    int* __restrict__ btot, int nchunk){
  __shared__ int s[512];
  int b = blockIdx.x, tid = threadIdx.x;
  int v = (tid < nchunk) ? C[b * nchunk + tid] : 0;
  s[tid] = v; __syncthreads();
  #pragma unroll
  for (int off = 1; off < 512; off <<= 1){
    int t = (tid >= off) ? s[tid - off] : 0;
    __syncthreads();
    s[tid] += t;
    __syncthreads();
  }
  if (tid < nchunk) C[b * nchunk + tid] = s[tid] - v;   // exclusive
  if (tid == 511) btot[b] = s[511];
}

// exclusive scan of bucket totals -> gbase[nbkt+1]  (nbkt <= 256)
__global__ __launch_bounds__(256) void k_bscan(const int* __restrict__ btot,
    int* __restrict__ gbase, int nbkt){
  __shared__ int s[256];
  int tid = threadIdx.x;
  int v = (tid < nbkt) ? btot[tid] : 0;
  s[tid] = v; __syncthreads();
  #pragma unroll
  for (int off = 1; off < 256; off <<= 1){
    int t = (tid >= off) ? s[tid - off] : 0;
    __syncthreads();
    s[tid] += t;
    __syncthreads();
  }
  if (tid < nbkt) gbase[tid] = s[tid] - v;
  if (tid == 255) gbase[nbkt] = s[255];
}

// partition edges into dst-buckets at precomputed offsets (zero global atomics)
__global__ __launch_bounds__(256) void k_part(const int* __restrict__ src,
    const int* __restrict__ dst, const float* __restrict__ ea,
    const int* __restrict__ gbase, const int* __restrict__ C, int nchunk,
    int2* __restrict__ staging, int e, int nbkt){
  __shared__ int base[256], cnt[256];
  int tid = threadIdx.x, c = blockIdx.x;
  if (tid < nbkt){ base[tid] = gbase[tid] + C[tid * nchunk + c]; cnt[tid] = 0; }
  __syncthreads();
  int c0 = c * PCHUNK;
  int w0[PCHUNK / 256], w1[PCHUNK / 256], bk[PCHUNK / 256];
  #pragma unroll
  for (int k = 0; k < PCHUNK / 256; ++k){
    int i = c0 + tid + (k << 8);
    bk[k] = -1;
    if (i < e){
      int d = dst[i];
      bk[k] = d >> NPB_SHIFT;
      w0[k] = src[i] | ((d & (NPB - 1)) << 17);   // src<2^17, dloc<2^9
      w1[k] = __float_as_int(ea[i]);
    }
  }
  #pragma unroll
  for (int k = 0; k < PCHUNK / 256; ++k){
    if (bk[k] >= 0){
      int pos = base[bk[k]] + atomicAdd(&cnt[bk[k]], 1);
      staging[pos] = make_int2(w0[k], w1[k]);
    }
  }
}

// one block per bucket: LDS node histogram + scan -> rowptr; permute edges
// into exact CSR positions inside the bucket's 64KB window (single CU/XCD)
__global__ __launch_bounds__(512) void k_bucket(const int* __restrict__ gbase,
    const int2* __restrict__ staging, int2* __restrict__ edges,
    int* __restrict__ rowptr, int n, int nbkt){
  __shared__ int degL[NPB], sc[NPB];
  int b = blockIdx.x, tid = threadIdx.x;
  int node0 = b << NPB_SHIFT;
  int nn = min(NPB, n - node0);
  int base = gbase[b], endj = gbase[b + 1];
  degL[tid] = 0;
  __syncthreads();
  for (int j = base + tid; j < endj; j += NPB)
    atomicAdd(&degL[staging[j].x >> 17], 1);
  __syncthreads();
  int dv = degL[tid];
  sc[tid] = dv;
  __syncthreads();
  #pragma unroll
  for (int off = 1; off < NPB; off <<= 1){
    int t = (tid >= off) ? sc[tid - off] : 0;
    __syncthreads();
    sc[tid] += t;
    __syncthreads();
  }
  int ex = sc[tid] - dv;                 // exclusive start (local)
  if (tid < nn) rowptr[node0 + tid] = base + ex;
  if (b == nbkt - 1 && tid == 0) rowptr[n] = base + sc[NPB - 1];
  __syncthreads();
  degL[tid] = ex;                        // becomes per-node cursor
  __syncthreads();
  for (int j = base + tid; j < endj; j += NPB){
    int2 w = staging[j];
    int dloc = w.x >> 17;
    int pos = base + atomicAdd(&degL[dloc], 1);
    edges[pos] = make_int2(w.x & 0x1FFFF, w.y);
  }
}

// ---------------- fused per-node softmax + aggregation ----------------
__global__ __launch_bounds__(256) void k_node_fused(
    const int* __restrict__ rowptr, const int2* __restrict__ edges,
    const float* __restrict__ asrc, const float* __restrict__ adst,
    const float* __restrict__ ce, int ce_idx,
    const float* __restrict__ H, const float* __restrict__ bias,
    float* __restrict__ out, int n, int relu)
{
  int v = blockIdx.x * 4 + (threadIdx.x >> 6);
  int lane = threadIdx.x & 63;
  if (v >= n) return;
  int start = rowptr[v], end = rowptr[v + 1];
  int deg = end - start;
  float bv = bias[lane];
  if (deg == 0){
    float r = relu ? fmaxf(bv, 0.f) : bv;
    out[(size_t)v * D + lane] = r;
    return;
  }
  float adv = adst[v];
  float cev = ce[ce_idx];
  float acc = 0.f;
  float inv;
  if (deg <= 64){
    int my_s = 0; float my_a = -1e30f;
    if (lane < deg){
      int2 pr = edges[start + lane];
      my_s = pr.x;
      float a = asrc[pr.x] + adv + __int_as_float(pr.y) * cev;
      my_a = a > 0.f ? a : NEG_SLOPE * a;
    }
    float m = my_a;
    #pragma unroll
    for (int off = 32; off; off >>= 1) m = fmaxf(m, __shfl_xor(m, off));
    float my_e = (lane < deg) ? __expf(my_a - m) : 0.f;
    float ss = my_e;
    #pragma unroll
    for (int off = 32; off; off >>= 1) ss += __shfl_xor(ss, off);
    inv = 1.f / (ss + 1e-16f);
    for (int k = 0; k < deg; ++k){
      int s   = __shfl(my_s, k);
      float w = __shfl(my_e, k);
      acc = fmaf(H[(size_t)s * D + lane], w, acc);
    }
  } else {
    float m = -1e30f;
    for (int j = start + lane; j < end; j += 64){
      int2 pr = edges[j];
      float a = asrc[pr.x] + adv + __int_as_float(pr.y) * cev;
      a = a > 0.f ? a : NEG_SLOPE * a;
      m = fmaxf(m, a);
    }
    #pragma unroll
    for (int off = 32; off; off >>= 1) m = fmaxf(m, __shfl_xor(m, off));
    float ss = 0.f;
    for (int j0 = start; j0 < end; j0 += 64){
      int j = j0 + lane;
      int my_s = 0; float my_e = 0.f;
      if (j < end){
        int2 pr = edges[j];
        float a = asrc[pr.x] + adv + __int_as_float(pr.y) * cev;
        a = a > 0.f ? a : NEG_SLOPE * a;
        my_e = __expf(a - m);
        my_s = pr.x;
      }
      ss += my_e;
      int cnt = min(64, end - j0);
      for (int k = 0; k < cnt; ++k){
        int s   = __shfl(my_s, k);
        float w = __shfl(my_e, k);
        acc = fmaf(H[(size_t)s * D + lane], w, acc);
      }
    }
    #pragma unroll
    for (int off = 32; off; off >>= 1) ss += __shfl_xor(ss, off);
    inv = 1.f / (ss + 1e-16f);
  }
  float r = acc * inv + bv;
  if (relu) r = fmaxf(r, 0.f);
  out[(size_t)v * D + lane] = r;
}

extern "C" void kernel_launch(void* const* d_in, const int* in_sizes, int n_in,
                              void* d_out, int out_size, void* d_ws, size_t ws_size,
                              hipStream_t stream)
{
  const float* x    = (const float*)d_in[0];
  const int*   ei   = (const int*)d_in[1];    // integer inputs arrive as int32
  const float* ea   = (const float*)d_in[2];
  const float* W1   = (const float*)d_in[3];
  const float* We1  = (const float*)d_in[4];
  const float* as1  = (const float*)d_in[5];
  const float* ad1  = (const float*)d_in[6];
  const float* ae1  = (const float*)d_in[7];
  const float* b1   = (const float*)d_in[8];
  const float* W2   = (const float*)d_in[9];
  const float* We2  = (const float*)d_in[10];
  const float* as2  = (const float*)d_in[11];
  const float* ad2  = (const float*)d_in[12];
  const float* ae2  = (const float*)d_in[13];
  const float* b2   = (const float*)d_in[14];
  float* out = (float*)d_out;

  int n = in_sizes[0] / D;     // 100000
  int e = in_sizes[1] / 2;     // 1600000
  const int* srcp = ei;
  const int* dstp = ei + e;

  int nbkt   = (n + NPB - 1) / NPB;          // 196
  int nchunk = (e + PCHUNK - 1) / PCHUNK;    // 391  (must be <= 512)

  char* p = (char*)d_ws;
  float* buf_h   = (float*)p;  p += (size_t)n * D * 4;
  float* buf_x2  = (float*)p;  p += (size_t)n * D * 4;
  float* asrc    = (float*)p;  p += (size_t)n * 4;
  float* adst    = (float*)p;  p += (size_t)n * 4;
  int*   rowptr  = (int*)p;    p += (size_t)(n + 16) * 4;
  int*   gbase   = (int*)p;    p += (size_t)(nbkt + 4) * 4;
  int*   btot    = (int*)p;    p += (size_t)(nbkt + 4) * 4;
  int*   C       = (int*)p;    p += (size_t)nbkt * nchunk * 4;
  float* ce      = (float*)p;  p += 64;
  int2*  edges   = (int2*)p;   p += (size_t)e * 8;
  // staging aliases buf_x2: consumed by k_bucket before layer-1 writes buf_x2
  int2*  staging = (int2*)buf_x2;

  int gR = (n + 3) / 4;       // wave per node, 4 per block

  // ---- CSR build (contention-free radix partition) ----
  k_ce<<<1, 64, 0, stream>>>(We1, ae1, We2, ae2, ce);
  k_bhist<<<nchunk, 256, 0, stream>>>(dstp, C, nchunk, e, nbkt);
  k_cscan<<<nbkt, 512, 0, stream>>>(C, btot, nchunk);
  k_bscan<<<1, 256, 0, stream>>>(btot, gbase, nbkt);
  k_part<<<nchunk, 256, 0, stream>>>(srcp, dstp, ea, gbase, C, nchunk, staging, e, nbkt);
  k_bucket<<<nbkt, NPB, 0, stream>>>(gbase, staging, edges, rowptr, n, nbkt);

  // ---- layer 1 ----
  k_gemm_dots<<<1024, 256, 0, stream>>>(x, W1, as1, ad1, buf_h, asrc, adst, n);
  k_node_fused<<<gR, 256, 0, stream>>>(rowptr, edges, asrc, adst, ce, 0, buf_h, b1, buf_x2, n, 1);

  // ---- layer 2 ----
  k_gemm_dots<<<1024, 256, 0, stream>>>(buf_x2, W2, as2, ad2, buf_h, asrc, adst, n);
  k_node_fused<<<gR, 256, 0, stream>>>(rowptr, edges, asrc, adst, ce, 1, buf_h, b2, out, n, 0);
}

// Round 8
// 448.283 us; speedup vs baseline: 2.1624x; 1.2195x over previous
//
#include <hip/hip_runtime.h>
#include <stdint.h>

#define D 64
constexpr float NEG_SLOPE = 0.2f;
#define NPB_SHIFT 9
#define NPB 512          // nodes per bucket
#define PCHUNK 4096      // edges per partition chunk

// ce[l] = sum_d We_l[d] * ae_l[d]
__global__ void k_ce(const float* __restrict__ We1, const float* __restrict__ ae1,
                     const float* __restrict__ We2, const float* __restrict__ ae2,
                     float* __restrict__ ce){
  int lane = threadIdx.x;
  float p1 = We1[lane] * ae1[lane];
  float p2 = We2[lane] * ae2[lane];
  #pragma unroll
  for (int off = 32; off; off >>= 1){ p1 += __shfl_xor(p1, off); p2 += __shfl_xor(p2, off); }
  if (lane == 0){ ce[0] = p1; ce[1] = p2; }
}

// h = X @ W — persistent blocks; fused asrc/adst dot products
__global__ __launch_bounds__(256) void k_gemm_dots(
    const float* __restrict__ X, const float* __restrict__ W,
    const float* __restrict__ a_s, const float* __restrict__ a_d,
    float* __restrict__ H, float* __restrict__ asrc, float* __restrict__ adst, int n)
{
  __shared__ float sW[D * D];
  {
    const float4* Wv = (const float4*)W;
    float4* sWv = (float4*)sW;
    #pragma unroll
    for (int t = threadIdx.x; t < D * D / 4; t += 256) sWv[t] = Wv[t];
  }
  int lane = threadIdx.x & 63;
  int wid  = threadIdx.x >> 6;
  float asv = a_s[lane], adv = a_d[lane];
  __syncthreads();
  int stride = gridDim.x * 4;
  for (int r = blockIdx.x * 4 + wid; r < n; r += stride){
    float xv = X[(size_t)r * D + lane];
    float acc = 0.f;
    #pragma unroll
    for (int k = 0; k < D; ++k){
      float xk = __shfl(xv, k);
      acc = fmaf(xk, sW[k * D + lane], acc);
    }
    H[(size_t)r * D + lane] = acc;
    float ps = acc * asv, pd = acc * adv;
    #pragma unroll
    for (int off = 32; off; off >>= 1){ ps += __shfl_xor(ps, off); pd += __shfl_xor(pd, off); }
    if (lane == 0){ asrc[r] = ps; adst[r] = pd; }
  }
}

// ---------------- contention-free CSR build ----------------

// per-chunk bucket histogram -> C[b*nchunk + c]  (no global atomics)
__global__ __launch_bounds__(256) void k_bhist(const int* __restrict__ dst,
    int* __restrict__ C, int nchunk, int e, int nbkt){
  __shared__ int hist[256];
  int tid = threadIdx.x, c = blockIdx.x;
  if (tid < nbkt) hist[tid] = 0;
  __syncthreads();
  int c0 = c * PCHUNK;
  #pragma unroll
  for (int k = 0; k < PCHUNK / 256; ++k){
    int i = c0 + tid + (k << 8);
    if (i < e) atomicAdd(&hist[dst[i] >> NPB_SHIFT], 1);
  }
  __syncthreads();
  if (tid < nbkt) C[tid * nchunk + c] = hist[tid];
}

// per-bucket exclusive scan of C over chunks; bucket totals (nchunk <= 512)
__global__ __launch_bounds__(512) void k_cscan(int* __restrict__ C,
    int* __restrict__ btot, int nchunk){
  __shared__ int s[512];
  int b = blockIdx.x, tid = threadIdx.x;
  int v = (tid < nchunk) ? C[b * nchunk + tid] : 0;
  s[tid] = v; __syncthreads();
  #pragma unroll
  for (int off = 1; off < 512; off <<= 1){
    int t = (tid >= off) ? s[tid - off] : 0;
    __syncthreads();
    s[tid] += t;
    __syncthreads();
  }
  if (tid < nchunk) C[b * nchunk + tid] = s[tid] - v;   // exclusive
  if (tid == 511) btot[b] = s[511];
}

// exclusive scan of bucket totals -> gbase[nbkt+1]  (nbkt <= 256)
__global__ __launch_bounds__(256) void k_bscan(const int* __restrict__ btot,
    int* __restrict__ gbase, int nbkt){
  __shared__ int s[256];
  int tid = threadIdx.x;
  int v = (tid < nbkt) ? btot[tid] : 0;
  s[tid] = v; __syncthreads();
  #pragma unroll
  for (int off = 1; off < 256; off <<= 1){
    int t = (tid >= off) ? s[tid - off] : 0;
    __syncthreads();
    s[tid] += t;
    __syncthreads();
  }
  if (tid < nbkt) gbase[tid] = s[tid] - v;
  if (tid == 255) gbase[nbkt] = s[255];
}

// partition edges into dst-buckets at precomputed offsets (zero global atomics)
__global__ __launch_bounds__(256) void k_part(const int* __restrict__ src,
    const int* __restrict__ dst, const float* __restrict__ ea,
    const int* __restrict__ gbase, const int* __restrict__ C, int nchunk,
    int2* __restrict__ staging, int e, int nbkt){
  __shared__ int base[256], cnt[256];
  int tid = threadIdx.x, c = blockIdx.x;
  if (tid < nbkt){ base[tid] = gbase[tid] + C[tid * nchunk + c]; cnt[tid] = 0; }
  __syncthreads();
  int c0 = c * PCHUNK;
  int w0[PCHUNK / 256], w1[PCHUNK / 256], bk[PCHUNK / 256];
  #pragma unroll
  for (int k = 0; k < PCHUNK / 256; ++k){
    int i = c0 + tid + (k << 8);
    bk[k] = -1;
    if (i < e){
      int d = dst[i];
      bk[k] = d >> NPB_SHIFT;
      w0[k] = src[i] | ((d & (NPB - 1)) << 17);   // src<2^17, dloc<2^9
      w1[k] = __float_as_int(ea[i]);
    }
  }
  #pragma unroll
  for (int k = 0; k < PCHUNK / 256; ++k){
    if (bk[k] >= 0){
      int pos = base[bk[k]] + atomicAdd(&cnt[bk[k]], 1);
      staging[pos] = make_int2(w0[k], w1[k]);
    }
  }
}

// one block per bucket: LDS node histogram + scan -> rowptr; permute edges
// into exact CSR positions inside the bucket's 64KB window (single CU/XCD)
__global__ __launch_bounds__(512) void k_bucket(const int* __restrict__ gbase,
    const int2* __restrict__ staging, int2* __restrict__ edges,
    int* __restrict__ rowptr, int n, int nbkt){
  __shared__ int degL[NPB], sc[NPB];
  int b = blockIdx.x, tid = threadIdx.x;
  int node0 = b << NPB_SHIFT;
  int nn = min(NPB, n - node0);
  int base = gbase[b], endj = gbase[b + 1];
  degL[tid] = 0;
  __syncthreads();
  for (int j = base + tid; j < endj; j += NPB)
    atomicAdd(&degL[staging[j].x >> 17], 1);
  __syncthreads();
  int dv = degL[tid];
  sc[tid] = dv;
  __syncthreads();
  #pragma unroll
  for (int off = 1; off < NPB; off <<= 1){
    int t = (tid >= off) ? sc[tid - off] : 0;
    __syncthreads();
    sc[tid] += t;
    __syncthreads();
  }
  int ex = sc[tid] - dv;                 // exclusive start (local)
  if (tid < nn) rowptr[node0 + tid] = base + ex;
  if (b == nbkt - 1 && tid == 0) rowptr[n] = base + sc[NPB - 1];
  __syncthreads();
  degL[tid] = ex;                        // becomes per-node cursor
  __syncthreads();
  for (int j = base + tid; j < endj; j += NPB){
    int2 w = staging[j];
    int dloc = w.x >> 17;
    int pos = base + atomicAdd(&degL[dloc], 1);
    edges[pos] = make_int2(w.x & 0x1FFFF, w.y);
  }
}

// ---------------- fused per-node softmax + aggregation ----------------
// wave per node, lane=feature. Gather loop 8-way unrolled: 8 independent
// loads in flight per iteration (addresses from shfl of loop-invariant regs).
__global__ __launch_bounds__(256) void k_node_fused(
    const int* __restrict__ rowptr, const int2* __restrict__ edges,
    const float* __restrict__ asrc, const float* __restrict__ adst,
    const float* __restrict__ ce, int ce_idx,
    const float* __restrict__ H, const float* __restrict__ bias,
    float* __restrict__ out, int n, int relu)
{
  int v = blockIdx.x * 4 + (threadIdx.x >> 6);
  int lane = threadIdx.x & 63;
  if (v >= n) return;
  int start = rowptr[v], end = rowptr[v + 1];
  int deg = end - start;
  float bv = bias[lane];
  if (deg == 0){
    float r = relu ? fmaxf(bv, 0.f) : bv;
    out[(size_t)v * D + lane] = r;
    return;
  }
  float adv = adst[v];
  float cev = ce[ce_idx];
  float acc0 = 0.f, acc1 = 0.f, acc2 = 0.f, acc3 = 0.f;
  float inv;
  if (deg <= 64){
    int my_s = 0; float my_a = -1e30f;
    if (lane < deg){
      int2 pr = edges[start + lane];
      my_s = pr.x;
      float a = asrc[pr.x] + adv + __int_as_float(pr.y) * cev;
      my_a = a > 0.f ? a : NEG_SLOPE * a;
    }
    float m = my_a;
    #pragma unroll
    for (int off = 32; off; off >>= 1) m = fmaxf(m, __shfl_xor(m, off));
    float my_e = (lane < deg) ? __expf(my_a - m) : 0.f;
    float ss = my_e;
    #pragma unroll
    for (int off = 32; off; off >>= 1) ss += __shfl_xor(ss, off);
    inv = 1.f / (ss + 1e-16f);
    int k = 0;
    for (; k + 8 <= deg; k += 8){
      int s0 = __shfl(my_s, k+0), s1 = __shfl(my_s, k+1);
      int s2 = __shfl(my_s, k+2), s3 = __shfl(my_s, k+3);
      int s4 = __shfl(my_s, k+4), s5 = __shfl(my_s, k+5);
      int s6 = __shfl(my_s, k+6), s7 = __shfl(my_s, k+7);
      float w0 = __shfl(my_e, k+0), w1 = __shfl(my_e, k+1);
      float w2 = __shfl(my_e, k+2), w3 = __shfl(my_e, k+3);
      float w4 = __shfl(my_e, k+4), w5 = __shfl(my_e, k+5);
      float w6 = __shfl(my_e, k+6), w7 = __shfl(my_e, k+7);
      float h0 = H[(size_t)s0 * D + lane];
      float h1 = H[(size_t)s1 * D + lane];
      float h2 = H[(size_t)s2 * D + lane];
      float h3 = H[(size_t)s3 * D + lane];
      float h4 = H[(size_t)s4 * D + lane];
      float h5 = H[(size_t)s5 * D + lane];
      float h6 = H[(size_t)s6 * D + lane];
      float h7 = H[(size_t)s7 * D + lane];
      acc0 = fmaf(h0, w0, acc0); acc1 = fmaf(h1, w1, acc1);
      acc2 = fmaf(h2, w2, acc2); acc3 = fmaf(h3, w3, acc3);
      acc0 = fmaf(h4, w4, acc0); acc1 = fmaf(h5, w5, acc1);
      acc2 = fmaf(h6, w6, acc2); acc3 = fmaf(h7, w7, acc3);
    }
    for (; k + 2 <= deg; k += 2){
      int s0 = __shfl(my_s, k+0), s1 = __shfl(my_s, k+1);
      float w0 = __shfl(my_e, k+0), w1 = __shfl(my_e, k+1);
      float h0 = H[(size_t)s0 * D + lane];
      float h1 = H[(size_t)s1 * D + lane];
      acc0 = fmaf(h0, w0, acc0); acc1 = fmaf(h1, w1, acc1);
    }
    if (k < deg){
      int s0 = __shfl(my_s, k);
      float w0 = __shfl(my_e, k);
      acc0 = fmaf(H[(size_t)s0 * D + lane], w0, acc0);
    }
  } else {
    float m = -1e30f;
    for (int j = start + lane; j < end; j += 64){
      int2 pr = edges[j];
      float a = asrc[pr.x] + adv + __int_as_float(pr.y) * cev;
      a = a > 0.f ? a : NEG_SLOPE * a;
      m = fmaxf(m, a);
    }
    #pragma unroll
    for (int off = 32; off; off >>= 1) m = fmaxf(m, __shfl_xor(m, off));
    float ss = 0.f;
    for (int j0 = start; j0 < end; j0 += 64){
      int j = j0 + lane;
      int my_s = 0; float my_e = 0.f;
      if (j < end){
        int2 pr = edges[j];
        float a = asrc[pr.x] + adv + __int_as_float(pr.y) * cev;
        a = a > 0.f ? a : NEG_SLOPE * a;
        my_e = __expf(a - m);
        my_s = pr.x;
      }
      ss += my_e;
      int cnt = min(64, end - j0);
      int k = 0;
      for (; k + 4 <= cnt; k += 4){
        int s0 = __shfl(my_s, k+0), s1 = __shfl(my_s, k+1);
        int s2 = __shfl(my_s, k+2), s3 = __shfl(my_s, k+3);
        float w0 = __shfl(my_e, k+0), w1 = __shfl(my_e, k+1);
        float w2 = __shfl(my_e, k+2), w3 = __shfl(my_e, k+3);
        float h0 = H[(size_t)s0 * D + lane];
        float h1 = H[(size_t)s1 * D + lane];
        float h2 = H[(size_t)s2 * D + lane];
        float h3 = H[(size_t)s3 * D + lane];
        acc0 = fmaf(h0, w0, acc0); acc1 = fmaf(h1, w1, acc1);
        acc2 = fmaf(h2, w2, acc2); acc3 = fmaf(h3, w3, acc3);
      }
      for (; k < cnt; ++k){
        int s0 = __shfl(my_s, k);
        float w0 = __shfl(my_e, k);
        acc0 = fmaf(H[(size_t)s0 * D + lane], w0, acc0);
      }
    }
    #pragma unroll
    for (int off = 32; off; off >>= 1) ss += __shfl_xor(ss, off);
    inv = 1.f / (ss + 1e-16f);
  }
  float acc = (acc0 + acc1) + (acc2 + acc3);
  float r = acc * inv + bv;
  if (relu) r = fmaxf(r, 0.f);
  out[(size_t)v * D + lane] = r;
}

extern "C" void kernel_launch(void* const* d_in, const int* in_sizes, int n_in,
                              void* d_out, int out_size, void* d_ws, size_t ws_size,
                              hipStream_t stream)
{
  const float* x    = (const float*)d_in[0];
  const int*   ei   = (const int*)d_in[1];    // integer inputs arrive as int32
  const float* ea   = (const float*)d_in[2];
  const float* W1   = (const float*)d_in[3];
  const float* We1  = (const float*)d_in[4];
  const float* as1  = (const float*)d_in[5];
  const float* ad1  = (const float*)d_in[6];
  const float* ae1  = (const float*)d_in[7];
  const float* b1   = (const float*)d_in[8];
  const float* W2   = (const float*)d_in[9];
  const float* We2  = (const float*)d_in[10];
  const float* as2  = (const float*)d_in[11];
  const float* ad2  = (const float*)d_in[12];
  const float* ae2  = (const float*)d_in[13];
  const float* b2   = (const float*)d_in[14];
  float* out = (float*)d_out;

  int n = in_sizes[0] / D;     // 100000
  int e = in_sizes[1] / 2;     // 1600000
  const int* srcp = ei;
  const int* dstp = ei + e;

  int nbkt   = (n + NPB - 1) / NPB;          // 196
  int nchunk = (e + PCHUNK - 1) / PCHUNK;    // 391  (must be <= 512)

  char* p = (char*)d_ws;
  float* buf_h   = (float*)p;  p += (size_t)n * D * 4;
  float* buf_x2  = (float*)p;  p += (size_t)n * D * 4;
  float* asrc    = (float*)p;  p += (size_t)n * 4;
  float* adst    = (float*)p;  p += (size_t)n * 4;
  int*   rowptr  = (int*)p;    p += (size_t)(n + 16) * 4;
  int*   gbase   = (int*)p;    p += (size_t)(nbkt + 4) * 4;
  int*   btot    = (int*)p;    p += (size_t)(nbkt + 4) * 4;
  int*   C       = (int*)p;    p += (size_t)nbkt * nchunk * 4;
  float* ce      = (float*)p;  p += 64;
  int2*  edges   = (int2*)p;   p += (size_t)e * 8;
  // staging aliases buf_x2: consumed by k_bucket before layer-1 writes buf_x2
  int2*  staging = (int2*)buf_x2;

  int gR = (n + 3) / 4;       // wave per node, 4 per block

  // ---- CSR build (contention-free radix partition) ----
  k_ce<<<1, 64, 0, stream>>>(We1, ae1, We2, ae2, ce);
  k_bhist<<<nchunk, 256, 0, stream>>>(dstp, C, nchunk, e, nbkt);
  k_cscan<<<nbkt, 512, 0, stream>>>(C, btot, nchunk);
  k_bscan<<<1, 256, 0, stream>>>(btot, gbase, nbkt);
  k_part<<<nchunk, 256, 0, stream>>>(srcp, dstp, ea, gbase, C, nchunk, staging, e, nbkt);
  k_bucket<<<nbkt, NPB, 0, stream>>>(gbase, staging, edges, rowptr, n, nbkt);

  // ---- layer 1 ----
  k_gemm_dots<<<1024, 256, 0, stream>>>(x, W1, as1, ad1, buf_h, asrc, adst, n);
  k_node_fused<<<gR, 256, 0, stream>>>(rowptr, edges, asrc, adst, ce, 0, buf_h, b1, buf_x2, n, 1);

  // ---- layer 2 ----
  k_gemm_dots<<<1024, 256, 0, stream>>>(buf_x2, W2, as2, ad2, buf_h, asrc, adst, n);
  k_node_fused<<<gR, 256, 0, stream>>>(rowptr, edges, asrc, adst, ce, 1, buf_h, b2, out, n, 0);
}

// Round 9
// 445.173 us; speedup vs baseline: 2.1775x; 1.0070x over previous
//
#include <hip/hip_runtime.h>
#include <stdint.h>

#define D 64
constexpr float NEG_SLOPE = 0.2f;
#define NPB_SHIFT 9
#define NPB 512          // nodes per bucket
#define PCHUNK 4096      // edges per partition chunk

// ce[l] = sum_d We_l[d] * ae_l[d]
__global__ void k_ce(const float* __restrict__ We1, const float* __restrict__ ae1,
                     const float* __restrict__ We2, const float* __restrict__ ae2,
                     float* __restrict__ ce){
  int lane = threadIdx.x;
  float p1 = We1[lane] * ae1[lane];
  float p2 = We2[lane] * ae2[lane];
  #pragma unroll
  for (int off = 32; off; off >>= 1){ p1 += __shfl_xor(p1, off); p2 += __shfl_xor(p2, off); }
  if (lane == 0){ ce[0] = p1; ce[1] = p2; }
}

// h = X @ W — W column held in 64 VGPRs/lane (no LDS); 8 rows in flight
// per wave (8 indep acc chains); fused asrc/adst dot products.
__global__ __launch_bounds__(256) void k_gemm_dots(
    const float* __restrict__ X, const float* __restrict__ W,
    const float* __restrict__ a_s, const float* __restrict__ a_d,
    float* __restrict__ H, float* __restrict__ asrc, float* __restrict__ adst, int n)
{
  int lane = threadIdx.x & 63;
  int wid  = blockIdx.x * 4 + (threadIdx.x >> 6);
  int nw   = gridDim.x * 4;
  float Wc[64];
  #pragma unroll
  for (int k = 0; k < 64; ++k) Wc[k] = W[k * D + lane];   // coalesced, L2-hit
  float asv = a_s[lane], adv = a_d[lane];
  int ngrp = (n + 7) >> 3;
  for (int g = wid; g < ngrp; g += nw){
    int r0 = g << 3;
    if (r0 + 8 <= n){
      float xr[8], acc[8];
      #pragma unroll
      for (int j = 0; j < 8; ++j) xr[j] = X[(size_t)(r0 + j) * D + lane];
      #pragma unroll
      for (int j = 0; j < 8; ++j) acc[j] = 0.f;
      #pragma unroll
      for (int k = 0; k < 64; ++k){
        #pragma unroll
        for (int j = 0; j < 8; ++j)
          acc[j] = fmaf(__shfl(xr[j], k), Wc[k], acc[j]);  // readlane bcast
      }
      #pragma unroll
      for (int j = 0; j < 8; ++j) H[(size_t)(r0 + j) * D + lane] = acc[j];
      #pragma unroll
      for (int j = 0; j < 8; ++j){
        float ps = acc[j] * asv, pd = acc[j] * adv;
        #pragma unroll
        for (int off = 32; off; off >>= 1){ ps += __shfl_xor(ps, off); pd += __shfl_xor(pd, off); }
        if (lane == 0){ asrc[r0 + j] = ps; adst[r0 + j] = pd; }
      }
    } else {
      for (int j = 0; r0 + j < n; ++j){
        float xv = X[(size_t)(r0 + j) * D + lane];
        float acc = 0.f;
        #pragma unroll
        for (int k = 0; k < 64; ++k) acc = fmaf(__shfl(xv, k), Wc[k], acc);
        H[(size_t)(r0 + j) * D + lane] = acc;
        float ps = acc * asv, pd = acc * adv;
        #pragma unroll
        for (int off = 32; off; off >>= 1){ ps += __shfl_xor(ps, off); pd += __shfl_xor(pd, off); }
        if (lane == 0){ asrc[r0 + j] = ps; adst[r0 + j] = pd; }
      }
    }
  }
}

// ---------------- contention-free CSR build ----------------

// per-chunk bucket histogram -> C[b*nchunk + c]  (no global atomics)
__global__ __launch_bounds__(256) void k_bhist(const int* __restrict__ dst,
    int* __restrict__ C, int nchunk, int e, int nbkt){
  __shared__ int hist[256];
  int tid = threadIdx.x, c = blockIdx.x;
  if (tid < nbkt) hist[tid] = 0;
  __syncthreads();
  int c0 = c * PCHUNK;
  #pragma unroll
  for (int k = 0; k < PCHUNK / 256; ++k){
    int i = c0 + tid + (k << 8);
    if (i < e) atomicAdd(&hist[dst[i] >> NPB_SHIFT], 1);
  }
  __syncthreads();
  if (tid < nbkt) C[tid * nchunk + c] = hist[tid];
}

// per-bucket exclusive scan of C over chunks; bucket totals (nchunk <= 512)
__global__ __launch_bounds__(512) void k_cscan(int* __restrict__ C,
    int* __restrict__ btot, int nchunk){
  __shared__ int s[512];
  int b = blockIdx.x, tid = threadIdx.x;
  int v = (tid < nchunk) ? C[b * nchunk + tid] : 0;
  s[tid] = v; __syncthreads();
  #pragma unroll
  for (int off = 1; off < 512; off <<= 1){
    int t = (tid >= off) ? s[tid - off] : 0;
    __syncthreads();
    s[tid] += t;
    __syncthreads();
  }
  if (tid < nchunk) C[b * nchunk + tid] = s[tid] - v;   // exclusive
  if (tid == 511) btot[b] = s[511];
}

// exclusive scan of bucket totals -> gbase[nbkt+1]  (nbkt <= 256)
__global__ __launch_bounds__(256) void k_bscan(const int* __restrict__ btot,
    int* __restrict__ gbase, int nbkt){
  __shared__ int s[256];
  int tid = threadIdx.x;
  int v = (tid < nbkt) ? btot[tid] : 0;
  s[tid] = v; __syncthreads();
  #pragma unroll
  for (int off = 1; off < 256; off <<= 1){
    int t = (tid >= off) ? s[tid - off] : 0;
    __syncthreads();
    s[tid] += t;
    __syncthreads();
  }
  if (tid < nbkt) gbase[tid] = s[tid] - v;
  if (tid == 255) gbase[nbkt] = s[255];
}

// partition edges into dst-buckets at precomputed offsets (zero global atomics)
__global__ __launch_bounds__(256) void k_part(const int* __restrict__ src,
    const int* __restrict__ dst, const float* __restrict__ ea,
    const int* __restrict__ gbase, const int* __restrict__ C, int nchunk,
    int2* __restrict__ staging, int e, int nbkt){
  __shared__ int base[256], cnt[256];
  int tid = threadIdx.x, c = blockIdx.x;
  if (tid < nbkt){ base[tid] = gbase[tid] + C[tid * nchunk + c]; cnt[tid] = 0; }
  __syncthreads();
  int c0 = c * PCHUNK;
  int w0[PCHUNK / 256], w1[PCHUNK / 256], bk[PCHUNK / 256];
  #pragma unroll
  for (int k = 0; k < PCHUNK / 256; ++k){
    int i = c0 + tid + (k << 8);
    bk[k] = -1;
    if (i < e){
      int d = dst[i];
      bk[k] = d >> NPB_SHIFT;
      w0[k] = src[i] | ((d & (NPB - 1)) << 17);   // src<2^17, dloc<2^9
      w1[k] = __float_as_int(ea[i]);
    }
  }
  #pragma unroll
  for (int k = 0; k < PCHUNK / 256; ++k){
    if (bk[k] >= 0){
      int pos = base[bk[k]] + atomicAdd(&cnt[bk[k]], 1);
      staging[pos] = make_int2(w0[k], w1[k]);
    }
  }
}

// one block per bucket: LDS node histogram + scan -> rowptr; permute edges
// into exact CSR positions inside the bucket's 64KB window (single CU/XCD)
__global__ __launch_bounds__(512) void k_bucket(const int* __restrict__ gbase,
    const int2* __restrict__ staging, int2* __restrict__ edges,
    int* __restrict__ rowptr, int n, int nbkt){
  __shared__ int degL[NPB], sc[NPB];
  int b = blockIdx.x, tid = threadIdx.x;
  int node0 = b << NPB_SHIFT;
  int nn = min(NPB, n - node0);
  int base = gbase[b], endj = gbase[b + 1];
  degL[tid] = 0;
  __syncthreads();
  for (int j = base + tid; j < endj; j += NPB)
    atomicAdd(&degL[staging[j].x >> 17], 1);
  __syncthreads();
  int dv = degL[tid];
  sc[tid] = dv;
  __syncthreads();
  #pragma unroll
  for (int off = 1; off < NPB; off <<= 1){
    int t = (tid >= off) ? sc[tid - off] : 0;
    __syncthreads();
    sc[tid] += t;
    __syncthreads();
  }
  int ex = sc[tid] - dv;                 // exclusive start (local)
  if (tid < nn) rowptr[node0 + tid] = base + ex;
  if (b == nbkt - 1 && tid == 0) rowptr[n] = base + sc[NPB - 1];
  __syncthreads();
  degL[tid] = ex;                        // becomes per-node cursor
  __syncthreads();
  for (int j = base + tid; j < endj; j += NPB){
    int2 w = staging[j];
    int dloc = w.x >> 17;
    int pos = base + atomicAdd(&degL[dloc], 1);
    edges[pos] = make_int2(w.x & 0x1FFFF, w.y);
  }
}

// ---------------- fused per-node softmax + aggregation ----------------
// wave per node, lane=feature. Gather loop 8-way unrolled: 8 independent
// loads in flight per iteration (addresses from shfl of loop-invariant regs).
__global__ __launch_bounds__(256) void k_node_fused(
    const int* __restrict__ rowptr, const int2* __restrict__ edges,
    const float* __restrict__ asrc, const float* __restrict__ adst,
    const float* __restrict__ ce, int ce_idx,
    const float* __restrict__ H, const float* __restrict__ bias,
    float* __restrict__ out, int n, int relu)
{
  int v = blockIdx.x * 4 + (threadIdx.x >> 6);
  int lane = threadIdx.x & 63;
  if (v >= n) return;
  int start = rowptr[v], end = rowptr[v + 1];
  int deg = end - start;
  float bv = bias[lane];
  if (deg == 0){
    float r = relu ? fmaxf(bv, 0.f) : bv;
    out[(size_t)v * D + lane] = r;
    return;
  }
  float adv = adst[v];
  float cev = ce[ce_idx];
  float acc0 = 0.f, acc1 = 0.f, acc2 = 0.f, acc3 = 0.f;
  float inv;
  if (deg <= 64){
    int my_s = 0; float my_a = -1e30f;
    if (lane < deg){
      int2 pr = edges[start + lane];
      my_s = pr.x;
      float a = asrc[pr.x] + adv + __int_as_float(pr.y) * cev;
      my_a = a > 0.f ? a : NEG_SLOPE * a;
    }
    float m = my_a;
    #pragma unroll
    for (int off = 32; off; off >>= 1) m = fmaxf(m, __shfl_xor(m, off));
    float my_e = (lane < deg) ? __expf(my_a - m) : 0.f;
    float ss = my_e;
    #pragma unroll
    for (int off = 32; off; off >>= 1) ss += __shfl_xor(ss, off);
    inv = 1.f / (ss + 1e-16f);
    int k = 0;
    for (; k + 8 <= deg; k += 8){
      int s0 = __shfl(my_s, k+0), s1 = __shfl(my_s, k+1);
      int s2 = __shfl(my_s, k+2), s3 = __shfl(my_s, k+3);
      int s4 = __shfl(my_s, k+4), s5 = __shfl(my_s, k+5);
      int s6 = __shfl(my_s, k+6), s7 = __shfl(my_s, k+7);
      float w0 = __shfl(my_e, k+0), w1 = __shfl(my_e, k+1);
      float w2 = __shfl(my_e, k+2), w3 = __shfl(my_e, k+3);
      float w4 = __shfl(my_e, k+4), w5 = __shfl(my_e, k+5);
      float w6 = __shfl(my_e, k+6), w7 = __shfl(my_e, k+7);
      float h0 = H[(size_t)s0 * D + lane];
      float h1 = H[(size_t)s1 * D + lane];
      float h2 = H[(size_t)s2 * D + lane];
      float h3 = H[(size_t)s3 * D + lane];
      float h4 = H[(size_t)s4 * D + lane];
      float h5 = H[(size_t)s5 * D + lane];
      float h6 = H[(size_t)s6 * D + lane];
      float h7 = H[(size_t)s7 * D + lane];
      acc0 = fmaf(h0, w0, acc0); acc1 = fmaf(h1, w1, acc1);
      acc2 = fmaf(h2, w2, acc2); acc3 = fmaf(h3, w3, acc3);
      acc0 = fmaf(h4, w4, acc0); acc1 = fmaf(h5, w5, acc1);
      acc2 = fmaf(h6, w6, acc2); acc3 = fmaf(h7, w7, acc3);
    }
    for (; k + 2 <= deg; k += 2){
      int s0 = __shfl(my_s, k+0), s1 = __shfl(my_s, k+1);
      float w0 = __shfl(my_e, k+0), w1 = __shfl(my_e, k+1);
      float h0 = H[(size_t)s0 * D + lane];
      float h1 = H[(size_t)s1 * D + lane];
      acc0 = fmaf(h0, w0, acc0); acc1 = fmaf(h1, w1, acc1);
    }
    if (k < deg){
      int s0 = __shfl(my_s, k);
      float w0 = __shfl(my_e, k);
      acc0 = fmaf(H[(size_t)s0 * D + lane], w0, acc0);
    }
  } else {
    float m = -1e30f;
    for (int j = start + lane; j < end; j += 64){
      int2 pr = edges[j];
      float a = asrc[pr.x] + adv + __int_as_float(pr.y) * cev;
      a = a > 0.f ? a : NEG_SLOPE * a;
      m = fmaxf(m, a);
    }
    #pragma unroll
    for (int off = 32; off; off >>= 1) m = fmaxf(m, __shfl_xor(m, off));
    float ss = 0.f;
    for (int j0 = start; j0 < end; j0 += 64){
      int j = j0 + lane;
      int my_s = 0; float my_e = 0.f;
      if (j < end){
        int2 pr = edges[j];
        float a = asrc[pr.x] + adv + __int_as_float(pr.y) * cev;
        a = a > 0.f ? a : NEG_SLOPE * a;
        my_e = __expf(a - m);
        my_s = pr.x;
      }
      ss += my_e;
      int cnt = min(64, end - j0);
      int k = 0;
      for (; k + 4 <= cnt; k += 4){
        int s0 = __shfl(my_s, k+0), s1 = __shfl(my_s, k+1);
        int s2 = __shfl(my_s, k+2), s3 = __shfl(my_s, k+3);
        float w0 = __shfl(my_e, k+0), w1 = __shfl(my_e, k+1);
        float w2 = __shfl(my_e, k+2), w3 = __shfl(my_e, k+3);
        float h0 = H[(size_t)s0 * D + lane];
        float h1 = H[(size_t)s1 * D + lane];
        float h2 = H[(size_t)s2 * D + lane];
        float h3 = H[(size_t)s3 * D + lane];
        acc0 = fmaf(h0, w0, acc0); acc1 = fmaf(h1, w1, acc1);
        acc2 = fmaf(h2, w2, acc2); acc3 = fmaf(h3, w3, acc3);
      }
      for (; k < cnt; ++k){
        int s0 = __shfl(my_s, k);
        float w0 = __shfl(my_e, k);
        acc0 = fmaf(H[(size_t)s0 * D + lane], w0, acc0);
      }
    }
    #pragma unroll
    for (int off = 32; off; off >>= 1) ss += __shfl_xor(ss, off);
    inv = 1.f / (ss + 1e-16f);
  }
  float acc = (acc0 + acc1) + (acc2 + acc3);
  float r = acc * inv + bv;
  if (relu) r = fmaxf(r, 0.f);
  out[(size_t)v * D + lane] = r;
}

extern "C" void kernel_launch(void* const* d_in, const int* in_sizes, int n_in,
                              void* d_out, int out_size, void* d_ws, size_t ws_size,
                              hipStream_t stream)
{
  const float* x    = (const float*)d_in[0];
  const int*   ei   = (const int*)d_in[1];    // integer inputs arrive as int32
  const float* ea   = (const float*)d_in[2];
  const float* W1   = (const float*)d_in[3];
  const float* We1  = (const float*)d_in[4];
  const float* as1  = (const float*)d_in[5];
  const float* ad1  = (const float*)d_in[6];
  const float* ae1  = (const float*)d_in[7];
  const float* b1   = (const float*)d_in[8];
  const float* W2   = (const float*)d_in[9];
  const float* We2  = (const float*)d_in[10];
  const float* as2  = (const float*)d_in[11];
  const float* ad2  = (const float*)d_in[12];
  const float* ae2  = (const float*)d_in[13];
  const float* b2   = (const float*)d_in[14];
  float* out = (float*)d_out;

  int n = in_sizes[0] / D;     // 100000
  int e = in_sizes[1] / 2;     // 1600000
  const int* srcp = ei;
  const int* dstp = ei + e;

  int nbkt   = (n + NPB - 1) / NPB;          // 196
  int nchunk = (e + PCHUNK - 1) / PCHUNK;    // 391  (must be <= 512)

  char* p = (char*)d_ws;
  float* buf_h   = (float*)p;  p += (size_t)n * D * 4;
  float* buf_x2  = (float*)p;  p += (size_t)n * D * 4;
  float* asrc    = (float*)p;  p += (size_t)n * 4;
  float* adst    = (float*)p;  p += (size_t)n * 4;
  int*   rowptr  = (int*)p;    p += (size_t)(n + 16) * 4;
  int*   gbase   = (int*)p;    p += (size_t)(nbkt + 4) * 4;
  int*   btot    = (int*)p;    p += (size_t)(nbkt + 4) * 4;
  int*   C       = (int*)p;    p += (size_t)nbkt * nchunk * 4;
  float* ce      = (float*)p;  p += 64;
  int2*  edges   = (int2*)p;   p += (size_t)e * 8;
  // staging aliases buf_x2: consumed by k_bucket before layer-1 writes buf_x2
  int2*  staging = (int2*)buf_x2;

  int gR = (n + 3) / 4;       // wave per node, 4 per block

  // ---- CSR build (contention-free radix partition) ----
  k_ce<<<1, 64, 0, stream>>>(We1, ae1, We2, ae2, ce);
  k_bhist<<<nchunk, 256, 0, stream>>>(dstp, C, nchunk, e, nbkt);
  k_cscan<<<nbkt, 512, 0, stream>>>(C, btot, nchunk);
  k_bscan<<<1, 256, 0, stream>>>(btot, gbase, nbkt);
  k_part<<<nchunk, 256, 0, stream>>>(srcp, dstp, ea, gbase, C, nchunk, staging, e, nbkt);
  k_bucket<<<nbkt, NPB, 0, stream>>>(gbase, staging, edges, rowptr, n, nbkt);

  // ---- layer 1 ----
  k_gemm_dots<<<2048, 256, 0, stream>>>(x, W1, as1, ad1, buf_h, asrc, adst, n);
  k_node_fused<<<gR, 256, 0, stream>>>(rowptr, edges, asrc, adst, ce, 0, buf_h, b1, buf_x2, n, 1);

  // ---- layer 2 ----
  k_gemm_dots<<<2048, 256, 0, stream>>>(buf_x2, W2, as2, ad2, buf_h, asrc, adst, n);
  k_node_fused<<<gR, 256, 0, stream>>>(rowptr, edges, asrc, adst, ce, 1, buf_h, b2, out, n, 0);
}